// Round 9
// baseline (180.505 us; speedup 1.0000x reference)
//
#include <hip/hip_runtime.h>

// FastBEV backprojection for MI355X (gfx950).
// B=2, NCAM=6, C=64, FH=225, FW=400, NX=NY=200, NZ=12, STRIDE=4.
//
// Correctness (settled R5, absmax 0.0): ref = numpy float32 transliteration.
// The projection chain must compile EXACTLY as written: hipcc defaults to
// -ffp-contract=fast, so every fp32-sensitive function carries
// `#pragma clang fp contract(off)`.  DO NOT REMOVE THE PRAGMAS.
//
// R6: 4 quads/thread + chunked XCD swizzle + NT stores -> 249->191us.
// R7: in-register grid synthesis + division-free map   -> 191->178us.
// R8: 8 quads/thread + int32 addressing                -> 178->173us (FETCH up).
// R9: channel-grouped decomposition: one thread = one spatial quad x 8
//     channels. Map int4 read ONCE per 8 quads (map L2 traffic -87%),
//     index math amortized 8x, block spatial footprint back to 256 quads.
#pragma clang fp contract(off)

namespace {
constexpr int kFW = 400, kFH = 225;
constexpr int kNX = 200, kNY = 200, kNZ = 12;
constexpr int kNPTS = kNX * kNY * kNZ;           // 480000
constexpr int kB = 2, kNCAM = 6, kC = 64;
constexpr int kPlane = kFH * kFW;                // 90000
constexpr int kCamStride = kC * kPlane;          // 5,760,000 (feat cam stride)
constexpr int kBatchStride = kNCAM * kCamStride; // 34,560,000 (feat batch stride)
constexpr int kOutCh = kC * kNZ;                 // 768
constexpr long long kOutTotal = (long long)kB * kOutCh * kNY * kNX;  // 61,440,000
constexpr int kParamF = 48;  // floats per (b,cam) param block
constexpr int kX4 = kNX / 4;                     // 50
constexpr int kCG = 8;                           // channels per thread
// thread-position space: b(2) x c8(8) x z(12) x yv(200) x x4(50) = 1,920,000
constexpr int kPosTotal = kB * (kC / kCG) * kNZ * kNY * kX4;
constexpr int kGatherBlocks = kPosTotal / 256;   // 7500
constexpr int kNXCD = 8;
constexpr int kSwzQ = kGatherBlocks / kNXCD;     // 937
constexpr int kSwzR = kGatherBlocks % kNXCD;     // 4
}

typedef float f4v __attribute__((ext_vector_type(4)));

// ---------------- projection math (bit-exact vs numpy fp32) ----------------

__device__ __forceinline__ float dot3(float m0, float m1, float m2,
                                      float s0, float s1, float s2) {
#pragma clang fp contract(off)
    float t = m0 * s0;
    t = t + m1 * s1;
    t = t + m2 * s2;
    return t;
}

// numpy fp32 inv: OpenBLAS sgetrf + laswp + 2x strsm (reciprocal diagonal).
__device__ void gesv_inv3_f32(const float R[9], float out[9]) {
#pragma clang fp contract(off)
    float A[3][3] = {{R[0], R[1], R[2]}, {R[3], R[4], R[5]}, {R[6], R[7], R[8]}};
    int ipiv[3];
    #pragma unroll
    for (int j = 0; j < 3; ++j) {
        int jp = j;
        float amax = fabsf(A[j][j]);
        for (int i = j + 1; i < 3; ++i) {
            float v = fabsf(A[i][j]);
            if (v > amax) { amax = v; jp = i; }   // first strict max
        }
        ipiv[j] = jp;
        if (jp != j)
            for (int k = 0; k < 3; ++k) { float t = A[j][k]; A[j][k] = A[jp][k]; A[jp][k] = t; }
        float r = 1.0f / A[j][j];
        for (int i = j + 1; i < 3; ++i) A[i][j] = A[i][j] * r;
        for (int i = j + 1; i < 3; ++i)
            for (int k = j + 1; k < 3; ++k)
                A[i][k] = A[i][k] - A[i][j] * A[j][k];   // unfused (pragma)
    }
    float Bm[3][3] = {{1.f, 0.f, 0.f}, {0.f, 1.f, 0.f}, {0.f, 0.f, 1.f}};
    for (int j = 0; j < 3; ++j) {
        int jp = ipiv[j];
        if (jp != j)
            for (int n = 0; n < 3; ++n) { float t = Bm[j][n]; Bm[j][n] = Bm[jp][n]; Bm[jp][n] = t; }
    }
    for (int n = 0; n < 3; ++n)
        for (int j = 0; j < 3; ++j)
            for (int i = j + 1; i < 3; ++i)
                Bm[i][n] = __builtin_fmaf(-A[i][j], Bm[j][n], Bm[i][n]);
    float d0 = 1.0f / A[0][0];
    float d1 = 1.0f / A[1][1];
    float d2 = 1.0f / A[2][2];
    for (int n = 0; n < 3; ++n) {
        float x2 = Bm[2][n] * d2;
        Bm[2][n] = x2;
        Bm[1][n] = __builtin_fmaf(-A[1][2], x2, Bm[1][n]);
        Bm[0][n] = __builtin_fmaf(-A[0][2], x2, Bm[0][n]);
        float x1 = Bm[1][n] * d1;
        Bm[1][n] = x1;
        Bm[0][n] = __builtin_fmaf(-A[0][1], x1, Bm[0][n]);
        Bm[0][n] = Bm[0][n] * d0;
    }
    for (int i = 0; i < 3; ++i)
        for (int n = 0; n < 3; ++n) out[i * 3 + n] = Bm[i][n];
}

// Param block per (b,cam):
// [0..8] Rl  [9..11] tl  [12..14] tc  [15..23] inv  [24..32] Ks  [33..41] Ar  [42..44] at
__device__ void build_params(int b, int cam, const float* l2e, const float* c2e,
                             const float* intr, const float* aug, float* P) {
#pragma clang fp contract(off)
    const float* L  = l2e  + b * 16;
    const float* Cc = c2e  + (b * kNCAM + cam) * 16;
    const float* Kk = intr + (b * kNCAM + cam) * 9;
    const float* Au = aug  + (b * kNCAM + cam) * 16;
    float Rc[9];
    for (int i = 0; i < 3; ++i)
        for (int j = 0; j < 3; ++j) {
            P[i * 3 + j]      = L[i * 4 + j];
            Rc[i * 3 + j]     = Cc[i * 4 + j];
            P[33 + i * 3 + j] = Au[i * 4 + j];
        }
    for (int i = 0; i < 3; ++i) {
        P[9 + i]  = L[i * 4 + 3];
        P[12 + i] = Cc[i * 4 + 3];
        P[42 + i] = Au[i * 4 + 3];
    }
    gesv_inv3_f32(Rc, P + 15);
    for (int j = 0; j < 3; ++j) {
        P[24 + 0 * 3 + j] = Kk[0 * 3 + j] * 0.25f;
        P[24 + 1 * 3 + j] = Kk[1 * 3 + j] * 0.25f;
        P[24 + 2 * 3 + j] = Kk[2 * 3 + j] * 1.0f;
    }
}

__global__ void k_setup(const float* l2e, const float* c2e,
                        const float* intr, const float* aug, float* prm) {
    int t = threadIdx.x;
    if (t < kB * kNCAM)
        build_params(t / kNCAM, t % kNCAM, l2e, c2e, intr, aug, prm + t * kParamF);
}

// Returns cam*kCamStride + pix (batch-relative feat offset), or -1.
__device__ __forceinline__ int project_one(const float* P, const float e0,
                                           const float e1, const float e2) {
#pragma clang fp contract(off)
    float s0 = e0 - P[12];
    float s1 = e1 - P[13];
    float s2 = e2 - P[14];
    const float* Mi = P + 15;
    float c0 = dot3(Mi[0], Mi[1], Mi[2], s0, s1, s2);
    float c1 = dot3(Mi[3], Mi[4], Mi[5], s0, s1, s2);
    float c2 = dot3(Mi[6], Mi[7], Mi[8], s0, s1, s2);
    const float* Mk = P + 24;
    float k0 = dot3(Mk[0], Mk[1], Mk[2], c0, c1, c2);
    float k1 = dot3(Mk[3], Mk[4], Mk[5], c0, c1, c2);
    float k2 = dot3(Mk[6], Mk[7], Mk[8], c0, c1, c2);
    const float* Ma = P + 33;
    float a0 = dot3(Ma[0], Ma[1], Ma[2], k0, k1, k2) + P[42];
    float a1 = dot3(Ma[3], Ma[4], Ma[5], k0, k1, k2) + P[43];
    float a2 = dot3(Ma[6], Ma[7], Ma[8], k0, k1, k2) + P[44];
    float u = a0 / a2;
    float v = a1 / a2;
    float xr = rintf(u);   // np.round: half-to-even
    float yr = rintf(v);
    if (a2 > 0.0f && xr >= 0.0f && yr >= 0.0f && xr < (float)kFW && yr < (float)kFH)
        return (int)yr * kFW + (int)xr;
    return -1;
}

__device__ __forceinline__ void stage1(const float* P0, float q0, float q1, float q2,
                                       float* e) {
#pragma clang fp contract(off)
    for (int row = 0; row < 3; ++row) {
        float acc = dot3(P0[row * 3 + 0], P0[row * 3 + 1], P0[row * 3 + 2], q0, q1, q2);
        e[row] = acc + P0[9 + row];
    }
}

// map[b][z][y][x] = cam*kCamStride + pix, or -1. Grid points synthesized
// in-register (bit-exact: all reference pts values are fp32 halves).
__global__ __launch_bounds__(256) void k_project(const float* __restrict__ prm,
                                                 int* __restrict__ map) {
#pragma clang fp contract(off)
    int i = blockIdx.x * 256 + threadIdx.x;
    if (i >= kB * kNPTS) return;
    int b  = i / kNPTS;
    int r  = i - b * kNPTS;
    int gz = r / (kNY * kNX);
    int r2 = r - gz * (kNY * kNX);
    int gy = r2 / kNX;
    int gx = r2 - gy * kNX;

    float q0 = (float)gx * 0.5f - 50.0f;   // exact
    float q1 = (float)gy * 0.5f - 50.0f;   // exact
    float q2 = (float)gz * 0.5f - 3.0f;    // exact

    const float* Pb = prm + (b * kNCAM) * kParamF;
    float e[3];
    stage1(Pb, q0, q1, q2, e);

    int best = -1;
    for (int cam = 0; cam < kNCAM; ++cam) {
        int pix = project_one(Pb + cam * kParamF, e[0], e[1], e[2]);
        if (pix >= 0) best = cam * kCamStride + pix;   // last valid camera wins
    }
    map[i] = best;
}

// ---------------- gather, v6 ----------------
// One thread = one spatial quad x 8 channels: map int4 read once, 32
// gathers at deterministic c-stride, 8 coalesced NT float4 stores.
__global__ __launch_bounds__(256) void k_gather_v6(const float* __restrict__ feat,
                                                   const int* __restrict__ map,
                                                   float4* __restrict__ out4) {
    int bid = blockIdx.x;
    int xcd = bid & (kNXCD - 1);
    int idx = bid >> 3;
    int lb  = (xcd < kSwzR ? xcd * (kSwzQ + 1)
                           : kSwzR * (kSwzQ + 1) + (xcd - kSwzR) * kSwzQ) + idx;

    // pos -> (x4, yv, z, c8, b); x4 fastest for coalescing.
    int pos = lb * 256 + threadIdx.x;
    int x4 = pos % kX4;
    int t  = pos / kX4;
    int yv = t % kNY;  t /= kNY;
    int z  = t % kNZ;  t /= kNZ;
    int c8 = t % (kC / kCG);
    int b  = t / (kC / kCG);

    const int4 m4 = *(const int4*)(map + (((b * kNZ + z) * kNY + yv) * kNX) + x4 * 4);
    // feat base for ci-th channel: b*kBatchStride + (c8*8+ci)*kPlane (+ m)
    int fb = b * kBatchStride + (c8 * kCG) * kPlane;      // < 2^31
    // out4 base: (((b*kOutCh + (c8*8+ci)*kNZ + z)*kNY + yv)*kX4 + x4
    int ob = ((b * kOutCh + (c8 * kCG) * kNZ + z) * kNY + yv) * kX4 + x4;
    constexpr int kOutCStride = kNZ * kNY * kX4;          // 120000 quads per c

    #pragma unroll
    for (int ci = 0; ci < kCG; ++ci) {
        const int bf = fb + ci * kPlane;
        f4v v;
        v.x = (m4.x >= 0) ? feat[bf + m4.x] : 0.0f;
        v.y = (m4.y >= 0) ? feat[bf + m4.y] : 0.0f;
        v.z = (m4.z >= 0) ? feat[bf + m4.z] : 0.0f;
        v.w = (m4.w >= 0) ? feat[bf + m4.w] : 0.0f;
        __builtin_nontemporal_store(v, (f4v*)&out4[ob + ci * kOutCStride]);
    }
}

// Fallback if workspace too small: fused, params in LDS (unused in practice).
__global__ __launch_bounds__(256) void k_fused(const float* __restrict__ feat,
                                               const float* l2e, const float* c2e,
                                               const float* intr, const float* aug,
                                               float* __restrict__ out) {
#pragma clang fp contract(off)
    __shared__ float sprm[kB * kNCAM * kParamF];
    if (threadIdx.x < kB * kNCAM)
        build_params(threadIdx.x / kNCAM, threadIdx.x % kNCAM, l2e, c2e, intr, aug,
                     &sprm[threadIdx.x * kParamF]);
    __syncthreads();
    int o = blockIdx.x * 256 + threadIdx.x;
    if (o >= (int)kOutTotal) return;
    int xv = o % kNX;
    int t  = o / kNX;
    int yv = t % kNY;  t /= kNY;
    int ch = t % kOutCh;
    int b  = t / kOutCh;
    int c  = ch / kNZ;
    int z  = ch - c * kNZ;
    float q0 = (float)xv * 0.5f - 50.0f;
    float q1 = (float)yv * 0.5f - 50.0f;
    float q2 = (float)z  * 0.5f - 3.0f;
    const float* Pb = sprm + (b * kNCAM) * kParamF;
    float e[3];
    stage1(Pb, q0, q1, q2, e);
    int best = -1;
    for (int cam = 0; cam < kNCAM; ++cam) {
        int pix = project_one(Pb + cam * kParamF, e[0], e[1], e[2]);
        if (pix >= 0) best = cam * kCamStride + pix;
    }
    float val = 0.0f;
    if (best >= 0)
        val = feat[(long long)b * kBatchStride + (long long)c * kPlane + best];
    out[o] = val;
}

extern "C" void kernel_launch(void* const* d_in, const int* in_sizes, int n_in,
                              void* d_out, int out_size, void* d_ws, size_t ws_size,
                              hipStream_t stream) {
    const float* feat = (const float*)d_in[0];
    const float* l2e  = (const float*)d_in[2];
    const float* c2e  = (const float*)d_in[3];
    const float* intr = (const float*)d_in[4];
    const float* aug  = (const float*)d_in[5];
    float* out = (float*)d_out;

    const size_t need = 4096 + (size_t)kB * kNPTS * sizeof(int);
    if (ws_size >= need) {
        float* prm = (float*)d_ws;
        int* map   = (int*)((char*)d_ws + 4096);
        k_setup<<<1, 64, 0, stream>>>(l2e, c2e, intr, aug, prm);
        int nproj = kB * kNPTS;
        k_project<<<(nproj + 255) / 256, 256, 0, stream>>>(prm, map);
        k_gather_v6<<<kGatherBlocks, 256, 0, stream>>>(feat, map, (float4*)out);
    } else {
        int nout_blocks = (int)((kOutTotal + 255) / 256);
        k_fused<<<nout_blocks, 256, 0, stream>>>(feat, l2e, c2e, intr, aug, out);
    }
}

// Round 10
// 172.563 us; speedup vs baseline: 1.0460x; 1.0460x over previous
//
#include <hip/hip_runtime.h>

// FastBEV backprojection for MI355X (gfx950).
// B=2, NCAM=6, C=64, FH=225, FW=400, NX=NY=200, NZ=12, STRIDE=4.
//
// Correctness (settled R5, absmax 0.0): ref = numpy float32 transliteration.
// The projection chain must compile EXACTLY as written: hipcc defaults to
// -ffp-contract=fast, so every fp32-sensitive function carries
// `#pragma clang fp contract(off)`.  DO NOT REMOVE THE PRAGMAS.
//
// Perf history:
//   R6: 4 quads/thread + chunked XCD swizzle + NT stores -> 249->191us
//   R7: in-register grid synthesis + division-free map   -> 191->178us
//   R8: 8 quads/thread + int32 addressing                -> 178->173us  <== BEST
//   R9: channel-grouped (8 ch/thread)                    -> 181us REGRESSION
//       (wave working set spans 8 c-slices -> worse L2 locality; map re-reads
//        and VALU were never the bottleneck)
// R10: revert to R8 verbatim. Gather is structurally bound by divergent
//      L2-line transactions + NT write stream; no counter near saturation
//      that decomposition can fix.
#pragma clang fp contract(off)

namespace {
constexpr int kFW = 400, kFH = 225;
constexpr int kNX = 200, kNY = 200, kNZ = 12;
constexpr int kNPTS = kNX * kNY * kNZ;           // 480000
constexpr int kB = 2, kNCAM = 6, kC = 64;
constexpr int kPlane = kFH * kFW;                // 90000
constexpr int kCamStride = kC * kPlane;          // 5,760,000 (feat cam stride)
constexpr int kBatchStride = kNCAM * kCamStride; // 34,560,000 (feat batch stride)
constexpr int kOutCh = kC * kNZ;                 // 768
constexpr long long kOutTotal = (long long)kB * kOutCh * kNY * kNX;  // 61,440,000
constexpr int kParamF = 48;  // floats per (b,cam) param block
constexpr int kQuads = (int)(kOutTotal / 4);     // 15,360,000
constexpr int kQPT = 8;                          // quads per thread
constexpr int kQuadsPerBlock = 256 * kQPT;       // 2048
constexpr int kGatherBlocks = kQuads / kQuadsPerBlock;  // 7500
constexpr int kNXCD = 8;
constexpr int kSwzQ = kGatherBlocks / kNXCD;     // 937
constexpr int kSwzR = kGatherBlocks % kNXCD;     // 4
}

typedef float f4v __attribute__((ext_vector_type(4)));

// ---------------- projection math (bit-exact vs numpy fp32) ----------------

__device__ __forceinline__ float dot3(float m0, float m1, float m2,
                                      float s0, float s1, float s2) {
#pragma clang fp contract(off)
    float t = m0 * s0;
    t = t + m1 * s1;
    t = t + m2 * s2;
    return t;
}

// numpy fp32 inv: OpenBLAS sgetrf + laswp + 2x strsm (reciprocal diagonal).
__device__ void gesv_inv3_f32(const float R[9], float out[9]) {
#pragma clang fp contract(off)
    float A[3][3] = {{R[0], R[1], R[2]}, {R[3], R[4], R[5]}, {R[6], R[7], R[8]}};
    int ipiv[3];
    #pragma unroll
    for (int j = 0; j < 3; ++j) {
        int jp = j;
        float amax = fabsf(A[j][j]);
        for (int i = j + 1; i < 3; ++i) {
            float v = fabsf(A[i][j]);
            if (v > amax) { amax = v; jp = i; }   // first strict max
        }
        ipiv[j] = jp;
        if (jp != j)
            for (int k = 0; k < 3; ++k) { float t = A[j][k]; A[j][k] = A[jp][k]; A[jp][k] = t; }
        float r = 1.0f / A[j][j];
        for (int i = j + 1; i < 3; ++i) A[i][j] = A[i][j] * r;
        for (int i = j + 1; i < 3; ++i)
            for (int k = j + 1; k < 3; ++k)
                A[i][k] = A[i][k] - A[i][j] * A[j][k];   // unfused (pragma)
    }
    float Bm[3][3] = {{1.f, 0.f, 0.f}, {0.f, 1.f, 0.f}, {0.f, 0.f, 1.f}};
    for (int j = 0; j < 3; ++j) {
        int jp = ipiv[j];
        if (jp != j)
            for (int n = 0; n < 3; ++n) { float t = Bm[j][n]; Bm[j][n] = Bm[jp][n]; Bm[jp][n] = t; }
    }
    for (int n = 0; n < 3; ++n)
        for (int j = 0; j < 3; ++j)
            for (int i = j + 1; i < 3; ++i)
                Bm[i][n] = __builtin_fmaf(-A[i][j], Bm[j][n], Bm[i][n]);
    float d0 = 1.0f / A[0][0];
    float d1 = 1.0f / A[1][1];
    float d2 = 1.0f / A[2][2];
    for (int n = 0; n < 3; ++n) {
        float x2 = Bm[2][n] * d2;
        Bm[2][n] = x2;
        Bm[1][n] = __builtin_fmaf(-A[1][2], x2, Bm[1][n]);
        Bm[0][n] = __builtin_fmaf(-A[0][2], x2, Bm[0][n]);
        float x1 = Bm[1][n] * d1;
        Bm[1][n] = x1;
        Bm[0][n] = __builtin_fmaf(-A[0][1], x1, Bm[0][n]);
        Bm[0][n] = Bm[0][n] * d0;
    }
    for (int i = 0; i < 3; ++i)
        for (int n = 0; n < 3; ++n) out[i * 3 + n] = Bm[i][n];
}

// Param block per (b,cam):
// [0..8] Rl  [9..11] tl  [12..14] tc  [15..23] inv  [24..32] Ks  [33..41] Ar  [42..44] at
__device__ void build_params(int b, int cam, const float* l2e, const float* c2e,
                             const float* intr, const float* aug, float* P) {
#pragma clang fp contract(off)
    const float* L  = l2e  + b * 16;
    const float* Cc = c2e  + (b * kNCAM + cam) * 16;
    const float* Kk = intr + (b * kNCAM + cam) * 9;
    const float* Au = aug  + (b * kNCAM + cam) * 16;
    float Rc[9];
    for (int i = 0; i < 3; ++i)
        for (int j = 0; j < 3; ++j) {
            P[i * 3 + j]      = L[i * 4 + j];
            Rc[i * 3 + j]     = Cc[i * 4 + j];
            P[33 + i * 3 + j] = Au[i * 4 + j];
        }
    for (int i = 0; i < 3; ++i) {
        P[9 + i]  = L[i * 4 + 3];
        P[12 + i] = Cc[i * 4 + 3];
        P[42 + i] = Au[i * 4 + 3];
    }
    gesv_inv3_f32(Rc, P + 15);
    for (int j = 0; j < 3; ++j) {
        P[24 + 0 * 3 + j] = Kk[0 * 3 + j] * 0.25f;
        P[24 + 1 * 3 + j] = Kk[1 * 3 + j] * 0.25f;
        P[24 + 2 * 3 + j] = Kk[2 * 3 + j] * 1.0f;
    }
}

__global__ void k_setup(const float* l2e, const float* c2e,
                        const float* intr, const float* aug, float* prm) {
    int t = threadIdx.x;
    if (t < kB * kNCAM)
        build_params(t / kNCAM, t % kNCAM, l2e, c2e, intr, aug, prm + t * kParamF);
}

// Returns cam*kCamStride + pix (batch-relative feat offset), or -1.
__device__ __forceinline__ int project_one(const float* P, const float e0,
                                           const float e1, const float e2) {
#pragma clang fp contract(off)
    float s0 = e0 - P[12];
    float s1 = e1 - P[13];
    float s2 = e2 - P[14];
    const float* Mi = P + 15;
    float c0 = dot3(Mi[0], Mi[1], Mi[2], s0, s1, s2);
    float c1 = dot3(Mi[3], Mi[4], Mi[5], s0, s1, s2);
    float c2 = dot3(Mi[6], Mi[7], Mi[8], s0, s1, s2);
    const float* Mk = P + 24;
    float k0 = dot3(Mk[0], Mk[1], Mk[2], c0, c1, c2);
    float k1 = dot3(Mk[3], Mk[4], Mk[5], c0, c1, c2);
    float k2 = dot3(Mk[6], Mk[7], Mk[8], c0, c1, c2);
    const float* Ma = P + 33;
    float a0 = dot3(Ma[0], Ma[1], Ma[2], k0, k1, k2) + P[42];
    float a1 = dot3(Ma[3], Ma[4], Ma[5], k0, k1, k2) + P[43];
    float a2 = dot3(Ma[6], Ma[7], Ma[8], k0, k1, k2) + P[44];
    float u = a0 / a2;
    float v = a1 / a2;
    float xr = rintf(u);   // np.round: half-to-even
    float yr = rintf(v);
    if (a2 > 0.0f && xr >= 0.0f && yr >= 0.0f && xr < (float)kFW && yr < (float)kFH)
        return (int)yr * kFW + (int)xr;
    return -1;
}

__device__ __forceinline__ void stage1(const float* P0, float q0, float q1, float q2,
                                       float* e) {
#pragma clang fp contract(off)
    for (int row = 0; row < 3; ++row) {
        float acc = dot3(P0[row * 3 + 0], P0[row * 3 + 1], P0[row * 3 + 2], q0, q1, q2);
        e[row] = acc + P0[9 + row];
    }
}

// map[b][z][y][x] = cam*kCamStride + pix, or -1. Grid points synthesized
// in-register (bit-exact: all reference pts values are fp32 halves).
__global__ __launch_bounds__(256) void k_project(const float* __restrict__ prm,
                                                 int* __restrict__ map) {
#pragma clang fp contract(off)
    int i = blockIdx.x * 256 + threadIdx.x;
    if (i >= kB * kNPTS) return;
    int b  = i / kNPTS;
    int r  = i - b * kNPTS;
    int gz = r / (kNY * kNX);
    int r2 = r - gz * (kNY * kNX);
    int gy = r2 / kNX;
    int gx = r2 - gy * kNX;

    float q0 = (float)gx * 0.5f - 50.0f;   // exact
    float q1 = (float)gy * 0.5f - 50.0f;   // exact
    float q2 = (float)gz * 0.5f - 3.0f;    // exact

    const float* Pb = prm + (b * kNCAM) * kParamF;
    float e[3];
    stage1(Pb, q0, q1, q2, e);

    int best = -1;
    for (int cam = 0; cam < kNCAM; ++cam) {
        int pix = project_one(Pb + cam * kParamF, e[0], e[1], e[2]);
        if (pix >= 0) best = cam * kCamStride + pix;   // last valid camera wins
    }
    map[i] = best;
}

// ---------------- gather (R8 optimum) ----------------
// 8 quads/thread (32 outstanding gathers), bijective chunked XCD swizzle,
// int32 feat addressing, NT stores.
__global__ __launch_bounds__(256) void k_gather_v5(const float* __restrict__ feat,
                                                   const int* __restrict__ map,
                                                   float4* __restrict__ out4) {
    constexpr int kX4 = kNX / 4;                 // 50
    int bid = blockIdx.x;
    int xcd = bid & (kNXCD - 1);
    int idx = bid >> 3;
    int lb  = (xcd < kSwzR ? xcd * (kSwzQ + 1)
                           : kSwzR * (kSwzQ + 1) + (xcd - kSwzR) * kSwzQ) + idx;
    int base = lb * kQuadsPerBlock + threadIdx.x;

    int4 m[kQPT];
    int  cb[kQPT];
    int  o4s[kQPT];
    #pragma unroll
    for (int k = 0; k < kQPT; ++k) {
        int o4 = base + k * 256;
        o4s[k] = o4;
        int x4 = o4 % kX4;
        int t  = o4 / kX4;
        int yv = t % kNY;  t /= kNY;
        int ch = t % kOutCh;
        int b  = t / kOutCh;
        int c  = ch / kNZ;
        int z  = ch - c * kNZ;
        m[k] = *(const int4*)(map + (((b * kNZ + z) * kNY + yv) * kNX) + x4 * 4);
        cb[k] = b * kBatchStride + c * kPlane;   // < 2^31, int32 exact
    }
    #pragma unroll
    for (int k = 0; k < kQPT; ++k) {
        const int bf = cb[k];
        f4v v;
        v.x = (m[k].x >= 0) ? feat[bf + m[k].x] : 0.0f;
        v.y = (m[k].y >= 0) ? feat[bf + m[k].y] : 0.0f;
        v.z = (m[k].z >= 0) ? feat[bf + m[k].z] : 0.0f;
        v.w = (m[k].w >= 0) ? feat[bf + m[k].w] : 0.0f;
        __builtin_nontemporal_store(v, (f4v*)&out4[o4s[k]]);
    }
}

// Fallback if workspace too small: fused, params in LDS (unused in practice).
__global__ __launch_bounds__(256) void k_fused(const float* __restrict__ feat,
                                               const float* l2e, const float* c2e,
                                               const float* intr, const float* aug,
                                               float* __restrict__ out) {
#pragma clang fp contract(off)
    __shared__ float sprm[kB * kNCAM * kParamF];
    if (threadIdx.x < kB * kNCAM)
        build_params(threadIdx.x / kNCAM, threadIdx.x % kNCAM, l2e, c2e, intr, aug,
                     &sprm[threadIdx.x * kParamF]);
    __syncthreads();
    int o = blockIdx.x * 256 + threadIdx.x;
    if (o >= (int)kOutTotal) return;
    int xv = o % kNX;
    int t  = o / kNX;
    int yv = t % kNY;  t /= kNY;
    int ch = t % kOutCh;
    int b  = t / kOutCh;
    int c  = ch / kNZ;
    int z  = ch - c * kNZ;
    float q0 = (float)xv * 0.5f - 50.0f;
    float q1 = (float)yv * 0.5f - 50.0f;
    float q2 = (float)z  * 0.5f - 3.0f;
    const float* Pb = sprm + (b * kNCAM) * kParamF;
    float e[3];
    stage1(Pb, q0, q1, q2, e);
    int best = -1;
    for (int cam = 0; cam < kNCAM; ++cam) {
        int pix = project_one(Pb + cam * kParamF, e[0], e[1], e[2]);
        if (pix >= 0) best = cam * kCamStride + pix;
    }
    float val = 0.0f;
    if (best >= 0)
        val = feat[(long long)b * kBatchStride + (long long)c * kPlane + best];
    out[o] = val;
}

extern "C" void kernel_launch(void* const* d_in, const int* in_sizes, int n_in,
                              void* d_out, int out_size, void* d_ws, size_t ws_size,
                              hipStream_t stream) {
    const float* feat = (const float*)d_in[0];
    const float* l2e  = (const float*)d_in[2];
    const float* c2e  = (const float*)d_in[3];
    const float* intr = (const float*)d_in[4];
    const float* aug  = (const float*)d_in[5];
    float* out = (float*)d_out;

    const size_t need = 4096 + (size_t)kB * kNPTS * sizeof(int);
    if (ws_size >= need) {
        float* prm = (float*)d_ws;
        int* map   = (int*)((char*)d_ws + 4096);
        k_setup<<<1, 64, 0, stream>>>(l2e, c2e, intr, aug, prm);
        int nproj = kB * kNPTS;
        k_project<<<(nproj + 255) / 256, 256, 0, stream>>>(prm, map);
        k_gather_v5<<<kGatherBlocks, 256, 0, stream>>>(feat, map, (float4*)out);
    } else {
        int nout_blocks = (int)((kOutTotal + 255) / 256);
        k_fused<<<nout_blocks, 256, 0, stream>>>(feat, l2e, c2e, intr, aug, out);
    }
}